// Round 9
// baseline (1395.072 us; speedup 1.0000x reference)
//
#include <hip/hip_runtime.h>

#define NN 100000
#define NE 1600000
#define NG 512
#define FIN 64
#define HD 128
#define NSTEP 6
#define SCHUNK 1024
#define NBLK 98    // ceil(NN/SCHUNK)

typedef _Float16 f16x8 __attribute__((ext_vector_type(8)));
typedef _Float16 f16x4 __attribute__((ext_vector_type(4)));
typedef float    f32x4 __attribute__((ext_vector_type(4)));

__device__ __forceinline__ float sigm(float x) { return 1.f / (1.f + __expf(-x)); }
__device__ __forceinline__ float tanhfast(float x) { return 2.f / (1.f + __expf(-2.f * x)) - 1.f; }

// LDS tile index with XOR swizzle (128-col tiles, 16B chunks)
__device__ __forceinline__ int lidx(int r, int col) {
    return r * 128 + ((((col >> 3) ^ (r & 15)) << 3) | (col & 7));
}

// ---------------- CSR build ----------------
__global__ void k_count(const int* __restrict__ dst, int* __restrict__ counts) {
    int e = blockIdx.x * 256 + threadIdx.x;
    if (e < NE) atomicAdd(&counts[dst[e]], 1);
}

__global__ void k_scan1(const int* __restrict__ counts, int* __restrict__ indptr, int* __restrict__ aux) {
    __shared__ int sh[256];
    int blk = blockIdx.x, tid = threadIdx.x;
    int base = blk * SCHUNK + tid * 4;
    int v0 = 0, v1 = 0, v2 = 0, v3 = 0;
    if (base + 0 < NN) v0 = counts[base + 0];
    if (base + 1 < NN) v1 = counts[base + 1];
    if (base + 2 < NN) v2 = counts[base + 2];
    if (base + 3 < NN) v3 = counts[base + 3];
    int tsum = v0 + v1 + v2 + v3;
    sh[tid] = tsum;
    __syncthreads();
    for (int off = 1; off < 256; off <<= 1) {
        int t = (tid >= off) ? sh[tid - off] : 0;
        __syncthreads();
        sh[tid] += t;
        __syncthreads();
    }
    int excl = sh[tid] - tsum;
    if (base + 0 < NN) indptr[base + 0] = excl;
    if (base + 1 < NN) indptr[base + 1] = excl + v0;
    if (base + 2 < NN) indptr[base + 2] = excl + v0 + v1;
    if (base + 3 < NN) indptr[base + 3] = excl + v0 + v1 + v2;
    if (tid == 255) aux[blk] = sh[255];
}

__global__ void k_scan2(int* __restrict__ aux) {
    __shared__ int sh[128];
    int tid = threadIdx.x;
    int v = (tid < NBLK) ? aux[tid] : 0;
    sh[tid] = v;
    __syncthreads();
    for (int off = 1; off < 128; off <<= 1) {
        int t = (tid >= off) ? sh[tid - off] : 0;
        __syncthreads();
        sh[tid] += t;
        __syncthreads();
    }
    if (tid < NBLK) aux[tid] = sh[tid] - v;
}

__global__ void k_scan3(int* __restrict__ indptr, int* __restrict__ cursor, const int* __restrict__ aux) {
    int blk = blockIdx.x, tid = threadIdx.x;
    int off = aux[blk];
    int base = blk * SCHUNK + tid * 4;
#pragma unroll
    for (int i = 0; i < 4; ++i) {
        int idx = base + i;
        if (idx < NN) {
            int v = indptr[idx] + off;
            indptr[idx] = v;
            cursor[idx] = v;
        }
    }
    if (blk == 0 && tid == 0) indptr[NN] = NE;
}

// direct scatter fill: atomics spread over 100k cursors (low contention).
// [R7 post-mortem: bucketed 2-pass with 782 counters was 3x WORSE - atomic serialization]
__global__ void k_fill(const int* __restrict__ src, const int* __restrict__ dst,
                       int* __restrict__ cursor, int* __restrict__ csr) {
    int e = blockIdx.x * 256 + threadIdx.x;
    if (e < NE) {
        int d = dst[e];
        int p = atomicAdd(&cursor[d], 1);
        csr[p] = src[e];
    }
}

// ---------------- B prep (GRU weights), swizzled to MFMA fragment order ----------------
// Logical Bcat[c][k]: c=0..511 (g=c>>7: 0=r,1=z,2=i_n,3=h_n; j=c&127), k=0..255.
//   k<128:  g!=3 ? Weff[s][k][jj] : 0    (Weff = Wmp[s] @ Wih^T)
//   k>=128: g!=2 ? Whh[jj][k-128] : 0
__global__ void k_prepB(const float* __restrict__ Wmp, const float* __restrict__ Wih,
                        const float* __restrict__ Whh, _Float16* __restrict__ Bsw) {
    __shared__ float wih[HD];
    int b = blockIdx.x;          // s*512 + c
    int s = b >> 9;
    int c = b & 511;
    int g = c >> 7;
    int j = c & 127;
    int jj = (g < 2) ? c : (j + 256);
    int k = threadIdx.x;         // 0..255
    if (k < HD) wih[k] = Wih[(size_t)jj * HD + k];
    __syncthreads();
    float val = 0.f;
    if (k < 128) {
        if (g != 3) {
            const float* wm = Wmp + ((size_t)s * HD + k) * HD;
            float acc = 0.f;
#pragma unroll 8
            for (int t = 0; t < HD; ++t) acc += wm[t] * wih[t];
            val = acc;
        }
    } else {
        if (g != 2) val = Whh[(size_t)jj * HD + (k - 128)];
    }
    int l16 = c & 15, sub = (c >> 4) & 1, w = (c >> 5) & 3;
    int t = g * 2 + sub;
    int p = k >> 5, quad = (k >> 3) & 3, je = k & 7;
    size_t idx = (size_t)s * 131072 + ((size_t)((w * 8 + t) * 8 + p) * 64 + quad * 16 + l16) * 8 + je;
    Bsw[idx] = (_Float16)val;
}

// ---------------- W_in prep: fragment-order hi/lo fp16 ----------------
__global__ void k_prepWin(const float* __restrict__ Win,
                          _Float16* __restrict__ BihW, _Float16* __restrict__ BilW) {
    int gid = blockIdx.x * 256 + threadIdx.x;   // 0..8191
    int jj = gid & 7;
    int lane = (gid >> 3) & 63;
    int p = (gid >> 9) & 1;
    int t = (gid >> 10) & 7;
    int k = p * 32 + (lane >> 4) * 8 + jj;
    int col = t * 16 + (lane & 15);
    float val = Win[(size_t)k * HD + col];
    _Float16 hi = (_Float16)val;
    BihW[gid] = hi;
    BilW[gid] = (_Float16)(val - (float)hi);
}

// ---------------- input layer (MFMA): h = tanh(x @ W_in), fp16 hi/lo out ----------------
__global__ void __launch_bounds__(256) k_input(const float* __restrict__ x,
                                               const _Float16* __restrict__ BihW,
                                               const _Float16* __restrict__ BilW,
                                               _Float16* __restrict__ Hhi, _Float16* __restrict__ Hlo) {
    __shared__ _Float16 Xh[64 * 64];
    __shared__ _Float16 Xl[64 * 64];
    __shared__ _Float16 Oh[64 * 128];
    __shared__ _Float16 Ol[64 * 128];
    int tid = threadIdx.x;
    int w = tid >> 6, lane = tid & 63;
    int quad = lane >> 4, l16 = lane & 15;
    int m0 = blockIdx.x * 64;

#pragma unroll
    for (int it = 0; it < 4; ++it) {
        int c = it * 256 + tid;          // 1024 chunks of 4 floats
        int row = c >> 4, cc = c & 15;
        int grow = m0 + row; if (grow >= NN) grow = NN - 1;
        float4 v = ((const float4*)(x + (size_t)grow * FIN))[cc];
        f16x4 vh, vl;
        vh[0] = (_Float16)v.x; vl[0] = (_Float16)(v.x - (float)vh[0]);
        vh[1] = (_Float16)v.y; vl[1] = (_Float16)(v.y - (float)vh[1]);
        vh[2] = (_Float16)v.z; vl[2] = (_Float16)(v.z - (float)vh[2]);
        vh[3] = (_Float16)v.w; vl[3] = (_Float16)(v.w - (float)vh[3]);
        int ld = row * 64 + ((((cc >> 1) ^ (row & 7)) << 3)) + (cc & 1) * 4;
        *(f16x4*)(&Xh[ld]) = vh;
        *(f16x4*)(&Xl[ld]) = vl;
    }
    __syncthreads();

    f32x4 acc[4][2];
#pragma unroll
    for (int mi = 0; mi < 4; ++mi) { acc[mi][0] = (f32x4){0,0,0,0}; acc[mi][1] = (f32x4){0,0,0,0}; }

#pragma unroll
    for (int p = 0; p < 2; ++p) {
        int ch = p * 4 + quad;
        f16x8 ah[4], al[4];
#pragma unroll
        for (int mi = 0; mi < 4; ++mi) {
            int r = mi * 16 + l16;
            int li = r * 64 + ((ch ^ (r & 7)) << 3);
            ah[mi] = *(const f16x8*)(&Xh[li]);
            al[mi] = *(const f16x8*)(&Xl[li]);
        }
#pragma unroll
        for (int t2 = 0; t2 < 2; ++t2) {
            int t = w * 2 + t2;
            f16x8 bh = *(const f16x8*)(BihW + ((size_t)(t * 2 + p) * 64 + lane) * 8);
            f16x8 blv = *(const f16x8*)(BilW + ((size_t)(t * 2 + p) * 64 + lane) * 8);
#pragma unroll
            for (int mi = 0; mi < 4; ++mi) {
                acc[mi][t2] = __builtin_amdgcn_mfma_f32_16x16x32_f16(ah[mi], bh, acc[mi][t2], 0, 0, 0);
                acc[mi][t2] = __builtin_amdgcn_mfma_f32_16x16x32_f16(ah[mi], blv, acc[mi][t2], 0, 0, 0);
                acc[mi][t2] = __builtin_amdgcn_mfma_f32_16x16x32_f16(al[mi], bh, acc[mi][t2], 0, 0, 0);
            }
        }
    }

#pragma unroll
    for (int t2 = 0; t2 < 2; ++t2) {
        int j = (w * 2 + t2) * 16 + l16;
#pragma unroll
        for (int mi = 0; mi < 4; ++mi) {
#pragma unroll
            for (int reg = 0; reg < 4; ++reg) {
                int row = mi * 16 + quad * 4 + reg;
                float v = tanhfast(acc[mi][t2][reg]);
                _Float16 hi = (_Float16)v;
                int li = lidx(row, j);
                Oh[li] = hi;
                Ol[li] = (_Float16)(v - (float)hi);
            }
        }
    }
    __syncthreads();
#pragma unroll
    for (int it = 0; it < 4; ++it) {
        int c = it * 256 + tid;
        int row = c >> 4, kc = c & 15;
        int grow = m0 + row;
        if (grow < NN) {
            int ld = row * 128 + ((kc ^ (row & 15)) << 3);
            size_t gdst = (size_t)grow * HD + kc * 8;
            *(f16x8*)(Hhi + gdst) = *(const f16x8*)(&Oh[ld]);
            *(f16x8*)(Hlo + gdst) = *(const f16x8*)(&Ol[ld]);
        }
    }
}

// ---------------- FUSED: gather-aggregate + MFMA GEMM + GRU gates ----------------
// Ping-pong: reads H from (Hrhi,Hrlo), writes new H to (Hwhi,Hwlo) -> no inter-block race.
// Per block (64 rows): stage own H rows to LDS; gather-aggregate S for own rows directly
// from global (random 256B rows, L2/L3) into LDS; then S/H MFMA phases as before.
// Epilogue does in-place LDS RMW (hold and out are the same li, one thread each).
__global__ void __launch_bounds__(256, 2) k_ggemm(
        const _Float16* __restrict__ Hrhi, const _Float16* __restrict__ Hrlo,
        _Float16* __restrict__ Hwhi, _Float16* __restrict__ Hwlo,
        const int* __restrict__ indptr, const int* __restrict__ csr,
        const _Float16* __restrict__ Bsw,
        const float* __restrict__ bih, const float* __restrict__ bhh) {
    __shared__ _Float16 Sl[64 * 128];
    __shared__ _Float16 Hh[64 * 128];
    __shared__ _Float16 Hl[64 * 128];
    int tid = threadIdx.x;
    int w = tid >> 6, lane = tid & 63;
    int quad = lane >> 4, l16 = lane & 15;
    int m0 = blockIdx.x * 64;

    // ---- stage own H rows (coalesced) ----
#pragma unroll
    for (int it = 0; it < 4; ++it) {
        int c = it * 256 + tid;
        int row = c >> 4, kc = c & 15;
        int grow = m0 + row; if (grow >= NN) grow = NN - 1;
        size_t gsrc = (size_t)grow * HD + kc * 8;
        int ld = row * 128 + ((kc ^ (row & 15)) << 3);
        *(f16x8*)(&Hh[ld]) = *(const f16x8*)(Hrhi + gsrc);
        *(f16x8*)(&Hl[ld]) = *(const f16x8*)(Hrlo + gsrc);
    }

    // ---- gather-aggregate S for own 64 rows ----
    // wave w handles block-local rows [w*16, w*16+16), 2 nodes at a time:
    // half=lane>>5 -> node parity; slot=(lane>>4)&1 -> edge parity; cg=lane&15 -> col group.
    {
        int half = lane >> 5, slot = (lane >> 4) & 1, cg = lane & 15;
        const _Float16* hp = Hrhi + cg * 8;
#pragma unroll 2
        for (int i2 = 0; i2 < 8; ++i2) {
            int r = w * 16 + i2 * 2 + half;
            int v = m0 + r; if (v >= NN) v = NN - 1;
            int s = indptr[v], e = indptr[v + 1];
            float a0 = 0.f, a1 = 0.f, a2 = 0.f, a3 = 0.f, a4 = 0.f, a5 = 0.f, a6 = 0.f, a7 = 0.f;
            int i = s + slot;
            for (; i + 6 < e; i += 8) {
                int u0 = csr[i], u1 = csr[i + 2], u2 = csr[i + 4], u3 = csr[i + 6];
                f16x8 t0 = *(const f16x8*)(hp + (size_t)u0 * HD);
                f16x8 t1 = *(const f16x8*)(hp + (size_t)u1 * HD);
                f16x8 t2 = *(const f16x8*)(hp + (size_t)u2 * HD);
                f16x8 t3 = *(const f16x8*)(hp + (size_t)u3 * HD);
                a0 += (float)t0[0] + (float)t1[0] + (float)t2[0] + (float)t3[0];
                a1 += (float)t0[1] + (float)t1[1] + (float)t2[1] + (float)t3[1];
                a2 += (float)t0[2] + (float)t1[2] + (float)t2[2] + (float)t3[2];
                a3 += (float)t0[3] + (float)t1[3] + (float)t2[3] + (float)t3[3];
                a4 += (float)t0[4] + (float)t1[4] + (float)t2[4] + (float)t3[4];
                a5 += (float)t0[5] + (float)t1[5] + (float)t2[5] + (float)t3[5];
                a6 += (float)t0[6] + (float)t1[6] + (float)t2[6] + (float)t3[6];
                a7 += (float)t0[7] + (float)t1[7] + (float)t2[7] + (float)t3[7];
            }
            for (; i < e; i += 2) {
                int u0 = csr[i];
                f16x8 t0 = *(const f16x8*)(hp + (size_t)u0 * HD);
                a0 += (float)t0[0]; a1 += (float)t0[1]; a2 += (float)t0[2]; a3 += (float)t0[3];
                a4 += (float)t0[4]; a5 += (float)t0[5]; a6 += (float)t0[6]; a7 += (float)t0[7];
            }
            // combine the two edge-parity slots (lanes 16 apart within each half)
            a0 += __shfl_down(a0, 16); a1 += __shfl_down(a1, 16);
            a2 += __shfl_down(a2, 16); a3 += __shfl_down(a3, 16);
            a4 += __shfl_down(a4, 16); a5 += __shfl_down(a5, 16);
            a6 += __shfl_down(a6, 16); a7 += __shfl_down(a7, 16);
            if (slot == 0) {
                f16x8 o;
                o[0] = (_Float16)a0; o[1] = (_Float16)a1; o[2] = (_Float16)a2; o[3] = (_Float16)a3;
                o[4] = (_Float16)a4; o[5] = (_Float16)a5; o[6] = (_Float16)a6; o[7] = (_Float16)a7;
                *(f16x8*)(&Sl[lidx(r, cg * 8)]) = o;
            }
        }
    }
    __syncthreads();

    f32x4 acc[4][8];
#pragma unroll
    for (int mi = 0; mi < 4; ++mi)
#pragma unroll
        for (int t = 0; t < 8; ++t) acc[mi][t] = (f32x4){0.f, 0.f, 0.f, 0.f};

    const _Float16* bw = Bsw + (size_t)(w * 8) * 8 * 512 + lane * 8;

    // S phases (1 product; gates r,z,i_n -> t=0..5)
#pragma unroll
    for (int p = 0; p < 4; ++p) {
        f16x8 a[4];
#pragma unroll
        for (int mi = 0; mi < 4; ++mi)
            a[mi] = *(const f16x8*)(&Sl[lidx(mi * 16 + l16, p * 32 + quad * 8)]);
#pragma unroll
        for (int t = 0; t < 6; ++t) {
            f16x8 b = *(const f16x8*)(bw + (size_t)(t * 8 + p) * 512);
#pragma unroll
            for (int mi = 0; mi < 4; ++mi)
                acc[mi][t] = __builtin_amdgcn_mfma_f32_16x16x32_f16(a[mi], b, acc[mi][t], 0, 0, 0);
        }
    }

    // H phases (hi/lo, 2 products; gates r,z,h_n -> t={0,1,2,3,6,7})
#pragma unroll
    for (int p = 0; p < 4; ++p) {
        f16x8 ah[4], al[4];
#pragma unroll
        for (int mi = 0; mi < 4; ++mi) {
            int li = lidx(mi * 16 + l16, p * 32 + quad * 8);
            ah[mi] = *(const f16x8*)(&Hh[li]);
            al[mi] = *(const f16x8*)(&Hl[li]);
        }
#pragma unroll
        for (int tt = 0; tt < 6; ++tt) {
            int t = (tt < 4) ? tt : (tt + 2);
            f16x8 b = *(const f16x8*)(bw + (size_t)(t * 8 + p + 4) * 512);
#pragma unroll
            for (int mi = 0; mi < 4; ++mi) {
                acc[mi][t] = __builtin_amdgcn_mfma_f32_16x16x32_f16(ah[mi], b, acc[mi][t], 0, 0, 0);
                acc[mi][t] = __builtin_amdgcn_mfma_f32_16x16x32_f16(al[mi], b, acc[mi][t], 0, 0, 0);
            }
        }
    }

    __syncthreads();   // all H-LDS A-reads done before epilogue overwrites Hh/Hl

    // epilogue: gates; hold RMW in place (each li touched by exactly one thread)
#pragma unroll
    for (int ns = 0; ns < 2; ++ns) {
        int j = w * 32 + ns * 16 + l16;
        float br  = bih[j]       + bhh[j];
        float bz  = bih[j + 128] + bhh[j + 128];
        float bin = bih[j + 256];
        float bhn = bhh[j + 256];
#pragma unroll
        for (int mi = 0; mi < 4; ++mi) {
#pragma unroll
            for (int reg = 0; reg < 4; ++reg) {
                int row = mi * 16 + quad * 4 + reg;
                int li = lidx(row, j);
                float hold = (float)Hh[li] + (float)Hl[li];
                float r = sigm(acc[mi][0 + ns][reg] + br);
                float z = sigm(acc[mi][2 + ns][reg] + bz);
                float n = tanhfast(acc[mi][4 + ns][reg] + bin + r * (acc[mi][6 + ns][reg] + bhn));
                float hnew = (1.f - z) * n + z * hold;
                _Float16 hi = (_Float16)hnew;
                Hh[li] = hi;
                Hl[li] = (_Float16)(hnew - (float)hi);
            }
        }
    }
    __syncthreads();

    // bulk coalesced store of the new H tile to the write buffers
#pragma unroll
    for (int it = 0; it < 4; ++it) {
        int c = it * 256 + tid;
        int row = c >> 4, kc = c & 15;
        int grow = m0 + row;
        if (grow < NN) {
            int ld = row * 128 + ((kc ^ (row & 15)) << 3);
            size_t gdst = (size_t)grow * HD + kc * 8;
            *(f16x8*)(Hwhi + gdst) = *(const f16x8*)(&Hh[ld]);
            *(f16x8*)(Hwlo + gdst) = *(const f16x8*)(&Hl[ld]);
        }
    }
}

// ---------------- pooling + head ----------------
__global__ void k_ginit(int* __restrict__ gs, int* __restrict__ ge) {
    int g = threadIdx.x;
    if (g < NG) { gs[g] = 0; ge[g] = 0; }
}

__global__ void k_bounds(const int* __restrict__ batch, int* __restrict__ gs, int* __restrict__ ge) {
    int i = blockIdx.x * 256 + threadIdx.x;
    if (i >= NN) return;
    int b = batch[i];
    if (i == 0 || batch[i - 1] != b) gs[b] = i;
    if (i == NN - 1 || batch[i + 1] != b) ge[b] = i + 1;
}

__global__ void k_pool(const _Float16* __restrict__ Hhi, const _Float16* __restrict__ Hlo,
                       const int* __restrict__ gs, const int* __restrict__ ge,
                       const float* __restrict__ Wp, const float* __restrict__ bp,
                       float* __restrict__ out) {
    __shared__ float red[HD];
    int g = blockIdx.x, tid = threadIdx.x;
    int s = gs[g], e = ge[g];
    float acc = 0.f;
    for (int n = s; n < e; ++n) {
        size_t idx = (size_t)n * HD + tid;
        acc += (float)Hhi[idx] + (float)Hlo[idx];
    }
    int cnt = e - s;
    float pooled = acc / (float)(cnt > 0 ? cnt : 1);
    red[tid] = fmaxf(pooled, 0.f) * Wp[tid];
    __syncthreads();
    for (int off = 64; off > 0; off >>= 1) {
        if (tid < off) red[tid] += red[tid + off];
        __syncthreads();
    }
    if (tid == 0) out[g] = red[0] + bp[0];
}

extern "C" void kernel_launch(void* const* d_in, const int* in_sizes, int n_in,
                              void* d_out, int out_size, void* d_ws, size_t ws_size,
                              hipStream_t stream) {
    const float* x   = (const float*)d_in[0];
    const int*   ei  = (const int*)d_in[1];
    const int*   bat = (const int*)d_in[2];
    const float* Win = (const float*)d_in[3];
    const float* Wmp = (const float*)d_in[4];
    const float* Wih = (const float*)d_in[5];
    const float* Whh = (const float*)d_in[6];
    const float* bih = (const float*)d_in[7];
    const float* bhh = (const float*)d_in[8];
    const float* Wp  = (const float*)d_in[9];
    const float* bp  = (const float*)d_in[10];
    float* out = (float*)d_out;

    const int* esrc = ei;
    const int* edst = ei + NE;

    char* w = (char*)d_ws;
    _Float16* H0hi = (_Float16*)w; w += (size_t)NN * HD * 2;
    _Float16* H0lo = (_Float16*)w; w += (size_t)NN * HD * 2;
    _Float16* H1hi = (_Float16*)w; w += (size_t)NN * HD * 2;
    _Float16* H1lo = (_Float16*)w; w += (size_t)NN * HD * 2;
    _Float16* Bsw = (_Float16*)w; w += (size_t)NSTEP * 131072 * 2;
    _Float16* BihW = (_Float16*)w; w += 8192 * 2;
    _Float16* BilW = (_Float16*)w; w += 8192 * 2;
    int* indptr  = (int*)w;   w += 400128;
    int* cursor  = (int*)w;   w += 400128;
    int* csr     = (int*)w;   w += (size_t)NE * 4;
    int* aux     = (int*)w;   w += 512;
    int* gs      = (int*)w;   w += NG * 4;
    int* ge      = (int*)w;   w += NG * 4;

    // CSR build (direct scatter; see k_fill comment)
    hipMemsetAsync(cursor, 0, (size_t)NN * 4, stream);
    k_count<<<NE / 256, 256, 0, stream>>>(edst, cursor);
    k_scan1<<<NBLK, 256, 0, stream>>>(cursor, indptr, aux);
    k_scan2<<<1, 128, 0, stream>>>(aux);
    k_scan3<<<NBLK, 256, 0, stream>>>(indptr, cursor, aux);
    k_fill<<<NE / 256, 256, 0, stream>>>(esrc, edst, cursor, csr);

    // weight prep + input layer (input writes H0)
    k_prepB<<<NSTEP * 512, 256, 0, stream>>>(Wmp, Wih, Whh, Bsw);
    k_prepWin<<<32, 256, 0, stream>>>(Win, BihW, BilW);
    k_input<<<(NN + 63) / 64, 256, 0, stream>>>(x, BihW, BilW, H0hi, H0lo);

    // 6 fused gather+GEMM/GRU steps, ping-pong H (even NSTEP -> final in H0)
    _Float16 *Rhi = H0hi, *Rlo = H0lo, *Whi = H1hi, *Wlo = H1lo;
    for (int st = 0; st < NSTEP; ++st) {
        k_ggemm<<<(NN + 63) / 64, 256, 0, stream>>>(Rhi, Rlo, Whi, Wlo, indptr, csr,
                                                    Bsw + (size_t)st * 131072,
                                                    bih, bhh);
        _Float16* t;
        t = Rhi; Rhi = Whi; Whi = t;
        t = Rlo; Rlo = Wlo; Wlo = t;
    }

    // pooling + head (final H is in H0 == Rhi/Rlo after 6 swaps)
    k_ginit<<<1, NG, 0, stream>>>(gs, ge);
    k_bounds<<<(NN + 255) / 256, 256, 0, stream>>>(bat, gs, ge);
    k_pool<<<NG, HD, 0, stream>>>(Rhi, Rlo, gs, ge, Wp, bp, out);
}

// Round 10
// 1161.317 us; speedup vs baseline: 1.2013x; 1.2013x over previous
//
#include <hip/hip_runtime.h>

#define NN 100000
#define NE 1600000
#define NG 512
#define FIN 64
#define HD 128
#define NSTEP 6
#define SCHUNK 1024
#define NBLK 98    // ceil(NN/SCHUNK)

typedef _Float16 f16x8 __attribute__((ext_vector_type(8)));
typedef _Float16 f16x4 __attribute__((ext_vector_type(4)));
typedef float    f32x4 __attribute__((ext_vector_type(4)));

__device__ __forceinline__ float sigm(float x) { return 1.f / (1.f + __expf(-x)); }
__device__ __forceinline__ float tanhfast(float x) { return 2.f / (1.f + __expf(-2.f * x)) - 1.f; }

// LDS tile index with XOR swizzle (128-col tiles, 16B chunks)
__device__ __forceinline__ int lidx(int r, int col) {
    return r * 128 + ((((col >> 3) ^ (r & 15)) << 3) | (col & 7));
}

// ---------------- CSR build ----------------
__global__ void k_count(const int* __restrict__ dst, int* __restrict__ counts) {
    int e = blockIdx.x * 256 + threadIdx.x;
    if (e < NE) atomicAdd(&counts[dst[e]], 1);
}

__global__ void k_scan1(const int* __restrict__ counts, int* __restrict__ indptr, int* __restrict__ aux) {
    __shared__ int sh[256];
    int blk = blockIdx.x, tid = threadIdx.x;
    int base = blk * SCHUNK + tid * 4;
    int v0 = 0, v1 = 0, v2 = 0, v3 = 0;
    if (base + 0 < NN) v0 = counts[base + 0];
    if (base + 1 < NN) v1 = counts[base + 1];
    if (base + 2 < NN) v2 = counts[base + 2];
    if (base + 3 < NN) v3 = counts[base + 3];
    int tsum = v0 + v1 + v2 + v3;
    sh[tid] = tsum;
    __syncthreads();
    for (int off = 1; off < 256; off <<= 1) {
        int t = (tid >= off) ? sh[tid - off] : 0;
        __syncthreads();
        sh[tid] += t;
        __syncthreads();
    }
    int excl = sh[tid] - tsum;
    if (base + 0 < NN) indptr[base + 0] = excl;
    if (base + 1 < NN) indptr[base + 1] = excl + v0;
    if (base + 2 < NN) indptr[base + 2] = excl + v0 + v1;
    if (base + 3 < NN) indptr[base + 3] = excl + v0 + v1 + v2;
    if (tid == 255) aux[blk] = sh[255];
}

__global__ void k_scan2(int* __restrict__ aux) {
    __shared__ int sh[128];
    int tid = threadIdx.x;
    int v = (tid < NBLK) ? aux[tid] : 0;
    sh[tid] = v;
    __syncthreads();
    for (int off = 1; off < 128; off <<= 1) {
        int t = (tid >= off) ? sh[tid - off] : 0;
        __syncthreads();
        sh[tid] += t;
        __syncthreads();
    }
    if (tid < NBLK) aux[tid] = sh[tid] - v;
}

__global__ void k_scan3(int* __restrict__ indptr, int* __restrict__ cursor, const int* __restrict__ aux) {
    int blk = blockIdx.x, tid = threadIdx.x;
    int off = aux[blk];
    int base = blk * SCHUNK + tid * 4;
#pragma unroll
    for (int i = 0; i < 4; ++i) {
        int idx = base + i;
        if (idx < NN) {
            int v = indptr[idx] + off;
            indptr[idx] = v;
            cursor[idx] = v;
        }
    }
    if (blk == 0 && tid == 0) indptr[NN] = NE;
}

// direct scatter fill: atomics spread over 100k cursors (low contention).
// [R7 post-mortem: bucketed 2-pass with 782 counters was 3x WORSE - atomic serialization]
__global__ void k_fill(const int* __restrict__ src, const int* __restrict__ dst,
                       int* __restrict__ cursor, int* __restrict__ csr) {
    int e = blockIdx.x * 256 + threadIdx.x;
    if (e < NE) {
        int d = dst[e];
        int p = atomicAdd(&cursor[d], 1);
        csr[p] = src[e];
    }
}

// ---------------- B prep (GRU weights), swizzled to MFMA fragment order ----------------
// Logical Bcat[c][k]: c=0..511 (g=c>>7: 0=r,1=z,2=i_n,3=h_n; j=c&127), k=0..255.
//   k<128:  g!=3 ? Weff[s][k][jj] : 0    (Weff = Wmp[s] @ Wih^T)
//   k>=128: g!=2 ? Whh[jj][k-128] : 0
__global__ void k_prepB(const float* __restrict__ Wmp, const float* __restrict__ Wih,
                        const float* __restrict__ Whh, _Float16* __restrict__ Bsw) {
    __shared__ float wih[HD];
    int b = blockIdx.x;          // s*512 + c
    int s = b >> 9;
    int c = b & 511;
    int g = c >> 7;
    int j = c & 127;
    int jj = (g < 2) ? c : (j + 256);
    int k = threadIdx.x;         // 0..255
    if (k < HD) wih[k] = Wih[(size_t)jj * HD + k];
    __syncthreads();
    float val = 0.f;
    if (k < 128) {
        if (g != 3) {
            const float* wm = Wmp + ((size_t)s * HD + k) * HD;
            float acc = 0.f;
#pragma unroll 8
            for (int t = 0; t < HD; ++t) acc += wm[t] * wih[t];
            val = acc;
        }
    } else {
        if (g != 2) val = Whh[(size_t)jj * HD + (k - 128)];
    }
    int l16 = c & 15, sub = (c >> 4) & 1, w = (c >> 5) & 3;
    int t = g * 2 + sub;
    int p = k >> 5, quad = (k >> 3) & 3, je = k & 7;
    size_t idx = (size_t)s * 131072 + ((size_t)((w * 8 + t) * 8 + p) * 64 + quad * 16 + l16) * 8 + je;
    Bsw[idx] = (_Float16)val;
}

// ---------------- W_in prep: fragment-order hi/lo fp16 ----------------
__global__ void k_prepWin(const float* __restrict__ Win,
                          _Float16* __restrict__ BihW, _Float16* __restrict__ BilW) {
    int gid = blockIdx.x * 256 + threadIdx.x;   // 0..8191
    int jj = gid & 7;
    int lane = (gid >> 3) & 63;
    int p = (gid >> 9) & 1;
    int t = (gid >> 10) & 7;
    int k = p * 32 + (lane >> 4) * 8 + jj;
    int col = t * 16 + (lane & 15);
    float val = Win[(size_t)k * HD + col];
    _Float16 hi = (_Float16)val;
    BihW[gid] = hi;
    BilW[gid] = (_Float16)(val - (float)hi);
}

// ---------------- input layer (MFMA): h = tanh(x @ W_in), fp16 out ----------------
__global__ void __launch_bounds__(256) k_input(const float* __restrict__ x,
                                               const _Float16* __restrict__ BihW,
                                               const _Float16* __restrict__ BilW,
                                               _Float16* __restrict__ H) {
    __shared__ _Float16 Xh[64 * 64];
    __shared__ _Float16 Xl[64 * 64];
    __shared__ _Float16 Oh[64 * 128];
    int tid = threadIdx.x;
    int w = tid >> 6, lane = tid & 63;
    int quad = lane >> 4, l16 = lane & 15;
    int m0 = blockIdx.x * 64;

#pragma unroll
    for (int it = 0; it < 4; ++it) {
        int c = it * 256 + tid;          // 1024 chunks of 4 floats
        int row = c >> 4, cc = c & 15;
        int grow = m0 + row; if (grow >= NN) grow = NN - 1;
        float4 v = ((const float4*)(x + (size_t)grow * FIN))[cc];
        f16x4 vh, vl;
        vh[0] = (_Float16)v.x; vl[0] = (_Float16)(v.x - (float)vh[0]);
        vh[1] = (_Float16)v.y; vl[1] = (_Float16)(v.y - (float)vh[1]);
        vh[2] = (_Float16)v.z; vl[2] = (_Float16)(v.z - (float)vh[2]);
        vh[3] = (_Float16)v.w; vl[3] = (_Float16)(v.w - (float)vh[3]);
        int ld = row * 64 + ((((cc >> 1) ^ (row & 7)) << 3)) + (cc & 1) * 4;
        *(f16x4*)(&Xh[ld]) = vh;
        *(f16x4*)(&Xl[ld]) = vl;
    }
    __syncthreads();

    f32x4 acc[4][2];
#pragma unroll
    for (int mi = 0; mi < 4; ++mi) { acc[mi][0] = (f32x4){0,0,0,0}; acc[mi][1] = (f32x4){0,0,0,0}; }

#pragma unroll
    for (int p = 0; p < 2; ++p) {
        int ch = p * 4 + quad;
        f16x8 ah[4], al[4];
#pragma unroll
        for (int mi = 0; mi < 4; ++mi) {
            int r = mi * 16 + l16;
            int li = r * 64 + ((ch ^ (r & 7)) << 3);
            ah[mi] = *(const f16x8*)(&Xh[li]);
            al[mi] = *(const f16x8*)(&Xl[li]);
        }
#pragma unroll
        for (int t2 = 0; t2 < 2; ++t2) {
            int t = w * 2 + t2;
            f16x8 bh = *(const f16x8*)(BihW + ((size_t)(t * 2 + p) * 64 + lane) * 8);
            f16x8 blv = *(const f16x8*)(BilW + ((size_t)(t * 2 + p) * 64 + lane) * 8);
#pragma unroll
            for (int mi = 0; mi < 4; ++mi) {
                acc[mi][t2] = __builtin_amdgcn_mfma_f32_16x16x32_f16(ah[mi], bh, acc[mi][t2], 0, 0, 0);
                acc[mi][t2] = __builtin_amdgcn_mfma_f32_16x16x32_f16(ah[mi], blv, acc[mi][t2], 0, 0, 0);
                acc[mi][t2] = __builtin_amdgcn_mfma_f32_16x16x32_f16(al[mi], bh, acc[mi][t2], 0, 0, 0);
            }
        }
    }

#pragma unroll
    for (int t2 = 0; t2 < 2; ++t2) {
        int j = (w * 2 + t2) * 16 + l16;
#pragma unroll
        for (int mi = 0; mi < 4; ++mi) {
#pragma unroll
            for (int reg = 0; reg < 4; ++reg) {
                int row = mi * 16 + quad * 4 + reg;
                Oh[lidx(row, j)] = (_Float16)tanhfast(acc[mi][t2][reg]);
            }
        }
    }
    __syncthreads();
#pragma unroll
    for (int it = 0; it < 4; ++it) {
        int c = it * 256 + tid;
        int row = c >> 4, kc = c & 15;
        int grow = m0 + row;
        if (grow < NN) {
            int ld = row * 128 + ((kc ^ (row & 15)) << 3);
            *(f16x8*)(H + (size_t)grow * HD + kc * 8) = *(const f16x8*)(&Oh[ld]);
        }
    }
}

// ---------------- aggregation: S[v] = sum_{in-edges} H[src], fp16 out ----------------
// Wave per node; lane = edge-slot (lane>>4) x col-group (lane&15). 4 rows in flight/wave.
__global__ void k_agg(const _Float16* __restrict__ H, const int* __restrict__ indptr,
                      const int* __restrict__ csr, _Float16* __restrict__ Shi) {
    int v = blockIdx.x * 4 + (threadIdx.x >> 6);
    int lane = threadIdx.x & 63;
    int slot = lane >> 4;
    int cg = lane & 15;
    const _Float16* hp = H + cg * 8;
    int s = indptr[v], e = indptr[v + 1];
    float a0 = 0.f, a1 = 0.f, a2 = 0.f, a3 = 0.f, a4 = 0.f, a5 = 0.f, a6 = 0.f, a7 = 0.f;
    int i = s + slot;
    for (; i + 12 < e; i += 16) {
        int u0 = csr[i], u1 = csr[i + 4], u2 = csr[i + 8], u3 = csr[i + 12];
        f16x8 t0 = *(const f16x8*)(hp + (size_t)u0 * HD);
        f16x8 t1 = *(const f16x8*)(hp + (size_t)u1 * HD);
        f16x8 t2 = *(const f16x8*)(hp + (size_t)u2 * HD);
        f16x8 t3 = *(const f16x8*)(hp + (size_t)u3 * HD);
        a0 += (float)t0[0] + (float)t1[0] + (float)t2[0] + (float)t3[0];
        a1 += (float)t0[1] + (float)t1[1] + (float)t2[1] + (float)t3[1];
        a2 += (float)t0[2] + (float)t1[2] + (float)t2[2] + (float)t3[2];
        a3 += (float)t0[3] + (float)t1[3] + (float)t2[3] + (float)t3[3];
        a4 += (float)t0[4] + (float)t1[4] + (float)t2[4] + (float)t3[4];
        a5 += (float)t0[5] + (float)t1[5] + (float)t2[5] + (float)t3[5];
        a6 += (float)t0[6] + (float)t1[6] + (float)t2[6] + (float)t3[6];
        a7 += (float)t0[7] + (float)t1[7] + (float)t2[7] + (float)t3[7];
    }
    for (; i < e; i += 4) {
        int u0 = csr[i];
        f16x8 t0 = *(const f16x8*)(hp + (size_t)u0 * HD);
        a0 += (float)t0[0]; a1 += (float)t0[1]; a2 += (float)t0[2]; a3 += (float)t0[3];
        a4 += (float)t0[4]; a5 += (float)t0[5]; a6 += (float)t0[6]; a7 += (float)t0[7];
    }
    a0 += __shfl_down(a0, 32); a1 += __shfl_down(a1, 32);
    a2 += __shfl_down(a2, 32); a3 += __shfl_down(a3, 32);
    a4 += __shfl_down(a4, 32); a5 += __shfl_down(a5, 32);
    a6 += __shfl_down(a6, 32); a7 += __shfl_down(a7, 32);
    a0 += __shfl_down(a0, 16); a1 += __shfl_down(a1, 16);
    a2 += __shfl_down(a2, 16); a3 += __shfl_down(a3, 16);
    a4 += __shfl_down(a4, 16); a5 += __shfl_down(a5, 16);
    a6 += __shfl_down(a6, 16); a7 += __shfl_down(a7, 16);
    if (lane < 16) {
        f16x8 o;
        o[0] = (_Float16)a0; o[1] = (_Float16)a1; o[2] = (_Float16)a2; o[3] = (_Float16)a3;
        o[4] = (_Float16)a4; o[5] = (_Float16)a5; o[6] = (_Float16)a6; o[7] = (_Float16)a7;
        *(f16x8*)(Shi + (size_t)v * HD + cg * 8) = o;
    }
}

// ---------------- fused MFMA GEMM + GRU gates (H plain fp16, in place) ----------------
// Block: 64 rows x 512 gate-cols. S phases t=0..5 (r,z,i_n), H phases t={0,1,2,3,6,7}
// (r,z,h_n), both single-product fp16. hold from H-LDS; epilogue in-place RMW on Hh.
// 32KB LDS + <=170 VGPR -> 3 blocks/CU.
__global__ void __launch_bounds__(256, 3) k_ggemm(
        const _Float16* __restrict__ Shi, _Float16* __restrict__ H,
        const _Float16* __restrict__ Bsw,
        const float* __restrict__ bih, const float* __restrict__ bhh) {
    __shared__ _Float16 Sl[64 * 128];
    __shared__ _Float16 Hh[64 * 128];
    int tid = threadIdx.x;
    int w = tid >> 6, lane = tid & 63;
    int quad = lane >> 4, l16 = lane & 15;
    int m0 = blockIdx.x * 64;

#pragma unroll
    for (int it = 0; it < 4; ++it) {
        int c = it * 256 + tid;
        int row = c >> 4, kc = c & 15;
        int grow = m0 + row; if (grow >= NN) grow = NN - 1;
        size_t gsrc = (size_t)grow * HD + kc * 8;
        int ld = row * 128 + ((kc ^ (row & 15)) << 3);
        *(f16x8*)(&Sl[ld]) = *(const f16x8*)(Shi + gsrc);
        *(f16x8*)(&Hh[ld]) = *(const f16x8*)(H + gsrc);
    }
    __syncthreads();

    f32x4 acc[4][8];
#pragma unroll
    for (int mi = 0; mi < 4; ++mi)
#pragma unroll
        for (int t = 0; t < 8; ++t) acc[mi][t] = (f32x4){0.f, 0.f, 0.f, 0.f};

    const _Float16* bw = Bsw + (size_t)(w * 8) * 8 * 512 + lane * 8;

    // S phases (gates r,z,i_n -> t=0..5)
#pragma unroll
    for (int p = 0; p < 4; ++p) {
        f16x8 a[4];
#pragma unroll
        for (int mi = 0; mi < 4; ++mi)
            a[mi] = *(const f16x8*)(&Sl[lidx(mi * 16 + l16, p * 32 + quad * 8)]);
#pragma unroll
        for (int t = 0; t < 6; ++t) {
            f16x8 b = *(const f16x8*)(bw + (size_t)(t * 8 + p) * 512);
#pragma unroll
            for (int mi = 0; mi < 4; ++mi)
                acc[mi][t] = __builtin_amdgcn_mfma_f32_16x16x32_f16(a[mi], b, acc[mi][t], 0, 0, 0);
        }
    }

    // H phases (gates r,z,h_n -> t={0,1,2,3,6,7})
#pragma unroll
    for (int p = 0; p < 4; ++p) {
        f16x8 a[4];
#pragma unroll
        for (int mi = 0; mi < 4; ++mi)
            a[mi] = *(const f16x8*)(&Hh[lidx(mi * 16 + l16, p * 32 + quad * 8)]);
#pragma unroll
        for (int tt = 0; tt < 6; ++tt) {
            int t = (tt < 4) ? tt : (tt + 2);
            f16x8 b = *(const f16x8*)(bw + (size_t)(t * 8 + p + 4) * 512);
#pragma unroll
            for (int mi = 0; mi < 4; ++mi)
                acc[mi][t] = __builtin_amdgcn_mfma_f32_16x16x32_f16(a[mi], b, acc[mi][t], 0, 0, 0);
        }
    }

    __syncthreads();   // all H-LDS A-reads done before epilogue overwrites Hh

    // epilogue: gates; in-place RMW on Hh (each li touched by exactly one thread)
#pragma unroll
    for (int ns = 0; ns < 2; ++ns) {
        int j = w * 32 + ns * 16 + l16;
        float br  = bih[j]       + bhh[j];
        float bz  = bih[j + 128] + bhh[j + 128];
        float bin = bih[j + 256];
        float bhn = bhh[j + 256];
#pragma unroll
        for (int mi = 0; mi < 4; ++mi) {
#pragma unroll
            for (int reg = 0; reg < 4; ++reg) {
                int row = mi * 16 + quad * 4 + reg;
                int li = lidx(row, j);
                float hold = (float)Hh[li];
                float r = sigm(acc[mi][0 + ns][reg] + br);
                float z = sigm(acc[mi][2 + ns][reg] + bz);
                float n = tanhfast(acc[mi][4 + ns][reg] + bin + r * (acc[mi][6 + ns][reg] + bhn));
                Hh[li] = (_Float16)((1.f - z) * n + z * hold);
            }
        }
    }
    __syncthreads();

#pragma unroll
    for (int it = 0; it < 4; ++it) {
        int c = it * 256 + tid;
        int row = c >> 4, kc = c & 15;
        int grow = m0 + row;
        if (grow < NN) {
            int ld = row * 128 + ((kc ^ (row & 15)) << 3);
            *(f16x8*)(H + (size_t)grow * HD + kc * 8) = *(const f16x8*)(&Hh[ld]);
        }
    }
}

// ---------------- pooling + head ----------------
__global__ void k_ginit(int* __restrict__ gs, int* __restrict__ ge) {
    int g = threadIdx.x;
    if (g < NG) { gs[g] = 0; ge[g] = 0; }
}

__global__ void k_bounds(const int* __restrict__ batch, int* __restrict__ gs, int* __restrict__ ge) {
    int i = blockIdx.x * 256 + threadIdx.x;
    if (i >= NN) return;
    int b = batch[i];
    if (i == 0 || batch[i - 1] != b) gs[b] = i;
    if (i == NN - 1 || batch[i + 1] != b) ge[b] = i + 1;
}

__global__ void k_pool(const _Float16* __restrict__ H,
                       const int* __restrict__ gs, const int* __restrict__ ge,
                       const float* __restrict__ Wp, const float* __restrict__ bp,
                       float* __restrict__ out) {
    __shared__ float red[HD];
    int g = blockIdx.x, tid = threadIdx.x;
    int s = gs[g], e = ge[g];
    float acc = 0.f;
    for (int n = s; n < e; ++n) acc += (float)H[(size_t)n * HD + tid];
    int cnt = e - s;
    float pooled = acc / (float)(cnt > 0 ? cnt : 1);
    red[tid] = fmaxf(pooled, 0.f) * Wp[tid];
    __syncthreads();
    for (int off = 64; off > 0; off >>= 1) {
        if (tid < off) red[tid] += red[tid + off];
        __syncthreads();
    }
    if (tid == 0) out[g] = red[0] + bp[0];
}

extern "C" void kernel_launch(void* const* d_in, const int* in_sizes, int n_in,
                              void* d_out, int out_size, void* d_ws, size_t ws_size,
                              hipStream_t stream) {
    const float* x   = (const float*)d_in[0];
    const int*   ei  = (const int*)d_in[1];
    const int*   bat = (const int*)d_in[2];
    const float* Win = (const float*)d_in[3];
    const float* Wmp = (const float*)d_in[4];
    const float* Wih = (const float*)d_in[5];
    const float* Whh = (const float*)d_in[6];
    const float* bih = (const float*)d_in[7];
    const float* bhh = (const float*)d_in[8];
    const float* Wp  = (const float*)d_in[9];
    const float* bp  = (const float*)d_in[10];
    float* out = (float*)d_out;

    const int* esrc = ei;
    const int* edst = ei + NE;

    char* w = (char*)d_ws;
    _Float16* H   = (_Float16*)w; w += (size_t)NN * HD * 2;
    _Float16* Shi = (_Float16*)w; w += (size_t)NN * HD * 2;
    _Float16* Bsw = (_Float16*)w; w += (size_t)NSTEP * 131072 * 2;
    _Float16* BihW = (_Float16*)w; w += 8192 * 2;
    _Float16* BilW = (_Float16*)w; w += 8192 * 2;
    int* indptr  = (int*)w;   w += 400128;
    int* cursor  = (int*)w;   w += 400128;
    int* csr     = (int*)w;   w += (size_t)NE * 4;
    int* aux     = (int*)w;   w += 512;
    int* gs      = (int*)w;   w += NG * 4;
    int* ge      = (int*)w;   w += NG * 4;

    // CSR build (direct scatter; see k_fill comment)
    hipMemsetAsync(cursor, 0, (size_t)NN * 4, stream);
    k_count<<<NE / 256, 256, 0, stream>>>(edst, cursor);
    k_scan1<<<NBLK, 256, 0, stream>>>(cursor, indptr, aux);
    k_scan2<<<1, 128, 0, stream>>>(aux);
    k_scan3<<<NBLK, 256, 0, stream>>>(indptr, cursor, aux);
    k_fill<<<NE / 256, 256, 0, stream>>>(esrc, edst, cursor, csr);

    // weight prep + input layer
    k_prepB<<<NSTEP * 512, 256, 0, stream>>>(Wmp, Wih, Whh, Bsw);
    k_prepWin<<<32, 256, 0, stream>>>(Win, BihW, BilW);
    k_input<<<(NN + 63) / 64, 256, 0, stream>>>(x, BihW, BilW, H);

    // 6 message-passing + fused GEMM/GRU steps (H updated in place)
    for (int st = 0; st < NSTEP; ++st) {
        k_agg<<<NN / 4, 256, 0, stream>>>(H, indptr, csr, Shi);
        k_ggemm<<<(NN + 63) / 64, 256, 0, stream>>>(Shi, H,
                                                    Bsw + (size_t)st * 131072,
                                                    bih, bhh);
    }

    // pooling + head
    k_ginit<<<1, NG, 0, stream>>>(gs, ge);
    k_bounds<<<(NN + 255) / 256, 256, 0, stream>>>(bat, gs, ge);
    k_pool<<<NG, HD, 0, stream>>>(H, gs, ge, Wp, bp, out);
}